// Round 1
// baseline (389.054 us; speedup 1.0000x reference)
//
#include <hip/hip_runtime.h>

// Axial attention (width axis), B=16 C=512 H=64 W=64 C8=64.
// One workgroup per (b,h): seq=64 attention with d_qk=64, d_v=512.
// Q/K projection + QK^T use split-bf16 (hi+lo, 3-term MFMA) for f32-grade scores
// (softmax here is near-one-hot; plain bf16 scores flip ties vs the f32 reference).
// V projection + AV use plain bf16 MFMA.

#define BDIM 512

typedef __attribute__((ext_vector_type(8))) short bf16x8;
typedef __attribute__((ext_vector_type(4))) float f32x4;

__device__ __forceinline__ unsigned short f2bf(float f){
  union { float f; unsigned u; } v; v.f = f;
  unsigned r = v.u + 0x7FFFu + ((v.u >> 16) & 1u);   // RNE
  return (unsigned short)(r >> 16);
}
__device__ __forceinline__ float bf2f(unsigned short b){
  union { unsigned u; float f; } v; v.u = ((unsigned)b) << 16; return v.f;
}

#define MFMA16(a, b, c) __builtin_amdgcn_mfma_f32_16x16x32_bf16((a), (b), (c), 0, 0, 0)

// ws layout (ushort elems): wq_hi@0  wq_lo@32768  wk_hi@65536  wk_lo@98304  wv@131072 (262144 elems)
__global__ void convert_w(const float* __restrict__ Wq, const float* __restrict__ Wk,
                          const float* __restrict__ Wv, unsigned short* __restrict__ wsw){
  const int stride = gridDim.x * blockDim.x;
  const int t0 = blockIdx.x * blockDim.x + threadIdx.x;
  for (int t = t0; t < 32768; t += stride){
    float f = Wq[t]; unsigned short h = f2bf(f);
    wsw[t] = h; wsw[32768 + t] = f2bf(f - bf2f(h));
    f = Wk[t]; h = f2bf(f);
    wsw[65536 + t] = h; wsw[98304 + t] = f2bf(f - bf2f(h));
  }
  for (int t = t0; t < 262144; t += stride)
    wsw[131072 + t] = f2bf(Wv[t]);
}

template<bool WS>
__global__ __launch_bounds__(BDIM)
void axial_attn(const float* __restrict__ x,
                const float* __restrict__ bq, const float* __restrict__ bk,
                const float* __restrict__ bv,
                const float* __restrict__ rel_h, const float* __restrict__ rel_w,
                const float* __restrict__ Wq, const float* __restrict__ Wk,
                const float* __restrict__ Wv,
                const unsigned short* __restrict__ wsw,
                float* __restrict__ out)
{
  extern __shared__ char smem[];
  // Persistent: x^T hi [64 w][520 c] bf16 (pad 8 -> 2-way bank alias on b128 reads = free)
  unsigned short* const xhi = (unsigned short*)smem;              // 66560 B
  char* const RB = smem + 66560;                                  // 87040 B region, phase-aliased
  // Phase 1 aliases:
  unsigned short* const xlo = (unsigned short*)RB;                // [64][136]
  unsigned short* const wqh = (unsigned short*)(RB + 17408);      // [64][136]
  unsigned short* const wql = (unsigned short*)(RB + 34816);
  unsigned short* const wkh = (unsigned short*)(RB + 52224);
  unsigned short* const wkl = (unsigned short*)(RB + 69632);
  // Phase 2 aliases:
  unsigned short* const Qh  = (unsigned short*)RB;                // [64][72]
  unsigned short* const Ql  = (unsigned short*)(RB + 9216);
  unsigned short* const Kh  = (unsigned short*)(RB + 18432);
  unsigned short* const Kl  = (unsigned short*)(RB + 27648);
  unsigned short* const att = (unsigned short*)(RB + 77824);      // [64][72] (stable through P3)
  // Phase 3 aliases:
  unsigned short* const wvb = (unsigned short*)RB;                // [64][520]
  unsigned short* const Vt  = (unsigned short*)(RB + 66560);      // [64][72]

  const int bid = blockIdx.x;
  const int b = bid >> 6, h = bid & 63;
  const int tid = threadIdx.x;
  const int wave = tid >> 6, lane = tid & 63;
  const int lg = lane >> 4, li = lane & 15;
  const int mt = wave >> 1;           // 16-row m-strip per wave
  const int npair = (wave & 1) * 2;   // first of this wave's two n-tiles

  const f32x4 z4 = {0.f, 0.f, 0.f, 0.f};
  f32x4 accQ[2] = {z4, z4}, accK[2] = {z4, z4};

  // ================= Phase 1: Q,K projection over c-chunks of 128 =================
  for (int cc = 0; cc < 4; ++cc){
    const int c0 = cc * 128;
    { // stage x chunk: global [c][w] f32 -> LDS [w][c] bf16 hi (persistent) + lo (chunk)
      const int w4 = (tid & 15) * 4;
      const int cb = tid >> 4;  // 0..31
      #pragma unroll
      for (int it = 0; it < 4; ++it){
        const int cl = cb + it * 32;
        const float4 v = *(const float4*)(x + (((b * 512 + c0 + cl) * 64 + h) * 64 + w4));
        const float ff[4] = {v.x, v.y, v.z, v.w};
        #pragma unroll
        for (int j = 0; j < 4; ++j){
          const unsigned short hi = f2bf(ff[j]);
          xhi[(w4 + j) * 520 + c0 + cl] = hi;
          xlo[(w4 + j) * 136 + cl] = f2bf(ff[j] - bf2f(hi));
        }
      }
    }
    if (WS){ // stage Wq/Wk hi/lo chunk from pre-converted ws (bf16)
      #pragma unroll
      for (int bi = 0; bi < 4; ++bi){
        unsigned short* const dst = (bi==0)?wqh:(bi==1)?wql:(bi==2)?wkh:wkl;
        const unsigned short* const src = wsw + bi * 32768;
        #pragma unroll
        for (int it = 0; it < 2; ++it){
          const int idx = tid + it * BDIM;
          const int o = idx >> 4, j8 = (idx & 15) * 8;
          *(int4*)(dst + o * 136 + j8) = *(const int4*)(src + o * 512 + c0 + j8);
        }
      }
    } else { // fallback: read f32 weights, convert inline
      #pragma unroll
      for (int mi = 0; mi < 2; ++mi){
        const float* const src = mi ? Wk : Wq;
        unsigned short* const dh = mi ? wkh : wqh;
        unsigned short* const dl = mi ? wkl : wql;
        #pragma unroll
        for (int it = 0; it < 2; ++it){
          const int idx = tid + it * BDIM;
          const int o = idx >> 4, j8 = (idx & 15) * 8;
          const float* const s2 = src + o * 512 + c0 + j8;
          const float4 f0 = *(const float4*)s2, f1 = *(const float4*)(s2 + 4);
          const float ff[8] = {f0.x,f0.y,f0.z,f0.w,f1.x,f1.y,f1.z,f1.w};
          union { unsigned short s[8]; int4 v; } ph, pl;
          #pragma unroll
          for (int j = 0; j < 8; ++j){
            ph.s[j] = f2bf(ff[j]);
            pl.s[j] = f2bf(ff[j] - bf2f(ph.s[j]));
          }
          *(int4*)(dh + o * 136 + j8) = ph.v;
          *(int4*)(dl + o * 136 + j8) = pl.v;
        }
      }
    }
    __syncthreads();
    // MFMA accumulate: Q/K[w,o] += X^T[w,c] * W^T[c,o], split 3-term
    const int arow = (mt * 16 + li) * 520 + c0;
    const int lrow = (mt * 16 + li) * 136;
    #pragma unroll
    for (int ks = 0; ks < 4; ++ks){
      const int ko = ks * 32 + lg * 8;
      const bf16x8 ah = *(const bf16x8*)(xhi + arow + ko);
      const bf16x8 al = *(const bf16x8*)(xlo + lrow + ko);
      #pragma unroll
      for (int nj = 0; nj < 2; ++nj){
        const int orow = ((npair + nj) * 16 + li) * 136 + ko;
        const bf16x8 bhq = *(const bf16x8*)(wqh + orow);
        const bf16x8 blq = *(const bf16x8*)(wql + orow);
        const bf16x8 bhk = *(const bf16x8*)(wkh + orow);
        const bf16x8 blk = *(const bf16x8*)(wkl + orow);
        accQ[nj] = MFMA16(ah, bhq, accQ[nj]);
        accQ[nj] = MFMA16(ah, blq, accQ[nj]);
        accQ[nj] = MFMA16(al, bhq, accQ[nj]);
        accK[nj] = MFMA16(ah, bhk, accK[nj]);
        accK[nj] = MFMA16(ah, blk, accK[nj]);
        accK[nj] = MFMA16(al, bhk, accK[nj]);
      }
    }
    __syncthreads();
  }

  // ============ Phase 1b: biases + write Q,K hi/lo to LDS [row][o] ============
  #pragma unroll
  for (int nj = 0; nj < 2; ++nj){
    const int o = (npair + nj) * 16 + li;
    const float qb = bq[o] + rel_h[o * 512 + h];
    const float bko = bk[o];
    #pragma unroll
    for (int r = 0; r < 4; ++r){
      const int row = mt * 16 + lg * 4 + r;       // w for Q, v for K
      const float qv = accQ[nj][r] + qb;
      const unsigned short qhi = f2bf(qv);
      Qh[row * 72 + o] = qhi;
      Ql[row * 72 + o] = f2bf(qv - bf2f(qhi));
      const float kv = accK[nj][r] + bko + rel_w[o * 512 + row];
      const unsigned short khi = f2bf(kv);
      Kh[row * 72 + o] = khi;
      Kl[row * 72 + o] = f2bf(kv - bf2f(khi));
    }
  }
  __syncthreads();

  // ============ Phase 2: S = Q K^T (split), softmax -> att (waves 0..3) ============
  if (wave < 4){
    f32x4 s[4] = {z4, z4, z4, z4};
    #pragma unroll
    for (int ks = 0; ks < 2; ++ks){
      const int ko = ks * 32 + lg * 8;
      const bf16x8 aqh = *(const bf16x8*)(Qh + (wave * 16 + li) * 72 + ko);
      const bf16x8 aql = *(const bf16x8*)(Ql + (wave * 16 + li) * 72 + ko);
      #pragma unroll
      for (int nt = 0; nt < 4; ++nt){
        const bf16x8 bh = *(const bf16x8*)(Kh + (nt * 16 + li) * 72 + ko);
        const bf16x8 bl = *(const bf16x8*)(Kl + (nt * 16 + li) * 72 + ko);
        s[nt] = MFMA16(aqh, bh, s[nt]);
        s[nt] = MFMA16(aqh, bl, s[nt]);
        s[nt] = MFMA16(aql, bh, s[nt]);
      }
    }
    #pragma unroll
    for (int r = 0; r < 4; ++r){
      float mx = fmaxf(fmaxf(s[0][r], s[1][r]), fmaxf(s[2][r], s[3][r]));
      mx = fmaxf(mx, __shfl_xor(mx, 1));
      mx = fmaxf(mx, __shfl_xor(mx, 2));
      mx = fmaxf(mx, __shfl_xor(mx, 4));
      mx = fmaxf(mx, __shfl_xor(mx, 8));
      const float e0 = __expf(s[0][r] - mx), e1 = __expf(s[1][r] - mx);
      const float e2 = __expf(s[2][r] - mx), e3 = __expf(s[3][r] - mx);
      float sum = e0 + e1 + e2 + e3;
      sum += __shfl_xor(sum, 1); sum += __shfl_xor(sum, 2);
      sum += __shfl_xor(sum, 4); sum += __shfl_xor(sum, 8);
      const float inv = 1.f / sum;
      const int row = wave * 16 + lg * 4 + r;
      att[row * 72 +  0 + li] = f2bf(e0 * inv);
      att[row * 72 + 16 + li] = f2bf(e1 * inv);
      att[row * 72 + 32 + li] = f2bf(e2 * inv);
      att[row * 72 + 48 + li] = f2bf(e3 * inv);
    }
  }
  __syncthreads();

  // ============ Phase 3: per d-chunk of 64: V-proj then AV ============
  for (int dc = 0; dc < 8; ++dc){
    const int d0 = dc * 64;
    if (WS){
      #pragma unroll
      for (int it = 0; it < 8; ++it){
        const int idx = tid + it * BDIM;
        const int d = idx >> 6, j8 = (idx & 63) * 8;
        *(int4*)(wvb + d * 520 + j8) =
          *(const int4*)(wsw + 131072 + (d0 + d) * 512 + j8);
      }
    } else {
      #pragma unroll
      for (int it = 0; it < 8; ++it){
        const int idx = tid + it * BDIM;
        const int d = idx >> 6, j8 = (idx & 63) * 8;
        const float* const s2 = Wv + (d0 + d) * 512 + j8;
        const float4 f0 = *(const float4*)s2, f1 = *(const float4*)(s2 + 4);
        const float ff[8] = {f0.x,f0.y,f0.z,f0.w,f1.x,f1.y,f1.z,f1.w};
        union { unsigned short s[8]; int4 v; } p;
        #pragma unroll
        for (int j = 0; j < 8; ++j) p.s[j] = f2bf(ff[j]);
        *(int4*)(wvb + d * 520 + j8) = p.v;
      }
    }
    __syncthreads();
    // V[v,d-chunk] = X^T[v,c] * Wv^T[c,d]
    f32x4 accV[2] = {z4, z4};
    const int vrow = (mt * 16 + li) * 520;
    #pragma unroll
    for (int ks = 0; ks < 16; ++ks){
      const int ko = ks * 32 + lg * 8;
      const bf16x8 a = *(const bf16x8*)(xhi + vrow + ko);
      #pragma unroll
      for (int nj = 0; nj < 2; ++nj){
        const bf16x8 bb = *(const bf16x8*)(wvb + ((npair + nj) * 16 + li) * 520 + ko);
        accV[nj] = MFMA16(a, bb, accV[nj]);
      }
    }
    // write V^T [d][v] bf16 (+bv); 4 consecutive v per lane -> one 8B store
    #pragma unroll
    for (int nj = 0; nj < 2; ++nj){
      const int d = (npair + nj) * 16 + li;
      const float bvd = bv[d0 + d];
      const int v0 = mt * 16 + lg * 4;
      union { unsigned short s[4]; uint2 v; } p;
      #pragma unroll
      for (int r = 0; r < 4; ++r) p.s[r] = f2bf(accV[nj][r] + bvd);
      *(uint2*)(Vt + d * 72 + v0) = p.v;
    }
    __syncthreads();
    // out[d,w] = V^T[d,v] * attn[w,v]  (A = Vt, B = att) -> coalesced-ish stores
    f32x4 accO[2] = {z4, z4};
    #pragma unroll
    for (int ks = 0; ks < 2; ++ks){
      const int ko = ks * 32 + lg * 8;
      const bf16x8 a = *(const bf16x8*)(Vt + (mt * 16 + li) * 72 + ko);
      #pragma unroll
      for (int nj = 0; nj < 2; ++nj){
        const bf16x8 bb = *(const bf16x8*)(att + ((npair + nj) * 16 + li) * 72 + ko);
        accO[nj] = MFMA16(a, bb, accO[nj]);
      }
    }
    #pragma unroll
    for (int nj = 0; nj < 2; ++nj){
      const int wcol = (npair + nj) * 16 + li;
      #pragma unroll
      for (int r = 0; r < 4; ++r){
        const int d = d0 + mt * 16 + lg * 4 + r;
        out[((b * 512 + d) * 64 + h) * 64 + wcol] = accO[nj][r];
      }
    }
    // no barrier needed: next iter's staging writes wvb only, and its post-stage
    // barrier orders it after all waves' AV reads of Vt/att.
  }
}

extern "C" void kernel_launch(void* const* d_in, const int* in_sizes, int n_in,
                              void* d_out, int out_size, void* d_ws, size_t ws_size,
                              hipStream_t stream){
  const float* x     = (const float*)d_in[0];
  const float* Wq    = (const float*)d_in[1];
  const float* bq    = (const float*)d_in[2];
  const float* Wk    = (const float*)d_in[3];
  const float* bk    = (const float*)d_in[4];
  const float* Wv    = (const float*)d_in[5];
  const float* bv    = (const float*)d_in[6];
  const float* rel_h = (const float*)d_in[7];
  const float* rel_w = (const float*)d_in[8];
  float* out = (float*)d_out;

  const dim3 grid(1024), blk(BDIM);
  const size_t smem = 153600;   // 150 KiB dynamic LDS -> 1 block/CU

  if (ws_size >= 786432){
    convert_w<<<1024, 256, 0, stream>>>(Wq, Wk, Wv, (unsigned short*)d_ws);
    axial_attn<true><<<grid, blk, smem, stream>>>(x, bq, bk, bv, rel_h, rel_w,
                                                  Wq, Wk, Wv,
                                                  (const unsigned short*)d_ws, out);
  } else {
    axial_attn<false><<<grid, blk, smem, stream>>>(x, bq, bk, bv, rel_h, rel_w,
                                                   Wq, Wk, Wv, nullptr, out);
  }
}

// Round 3
// 379.146 us; speedup vs baseline: 1.0261x; 1.0261x over previous
//
#include <hip/hip_runtime.h>

// Axial attention (width axis), B=16 C=512 H=64 W=64 C8=64.
// One workgroup per (b,h). Round 2 (resubmit; prior bench hit GPU-acquisition
// timeout): x A-frags in registers (64 VGPR), LDS 78.5KB -> 2 blocks/CU,
// conflict-free staging (lane=w scalar loads, 8B LDS writes), double-buffered
// Wv staging, float4 output stores.
// Q/K proj + QK^T in split-bf16 (hi+lo) for f32-grade scores (near-one-hot softmax).

#define BDIM 512

typedef __attribute__((ext_vector_type(8))) short bf16x8;
typedef __attribute__((ext_vector_type(4))) float f32x4;

__device__ __forceinline__ unsigned short f2bf(float f){
  union { float f; unsigned u; } v; v.f = f;
  unsigned r = v.u + 0x7FFFu + ((v.u >> 16) & 1u);   // RNE
  return (unsigned short)(r >> 16);
}
__device__ __forceinline__ float bf2f(unsigned short b){
  union { unsigned u; float f; } v; v.u = ((unsigned)b) << 16; return v.f;
}

#define MFMA16(a, b, c) __builtin_amdgcn_mfma_f32_16x16x32_bf16((a), (b), (c), 0, 0, 0)

// ---- LDS offsets in ushort units ----
// Phase 1 (per 64-c chunk): x hi/lo + Wq hi/lo + Wk hi/lo, each [64][72]
#define XH  0
#define XL  4608
#define WQH 9216
#define WQL 13824
#define WKH 18432
#define WKL 23040
// Phase 2: Q/K hi/lo [64][72] (alias), att stable at ATT
#define QH  0
#define QL  4608
#define KH  9216
#define KL  13824
// Phase 3: Wv double-buffer [32][520], Vt [32][72], att [64][72]
#define WVB0 0
#define WVB1 16640
#define VT   33280
#define ATT  35584
#define SMEM_BYTES 80384   // 78.5 KiB -> 2 blocks/CU

// ws layout (ushort elems): wq_hi@0 wq_lo@32768 wk_hi@65536 wk_lo@98304 wv@131072
__global__ void convert_w(const float* __restrict__ Wq, const float* __restrict__ Wk,
                          const float* __restrict__ Wv, unsigned short* __restrict__ wsw){
  const int stride = gridDim.x * blockDim.x;
  const int t0 = blockIdx.x * blockDim.x + threadIdx.x;
  for (int t = t0; t < 32768; t += stride){
    float f = Wq[t]; unsigned short h = f2bf(f);
    wsw[t] = h; wsw[32768 + t] = f2bf(f - bf2f(h));
    f = Wk[t]; h = f2bf(f);
    wsw[65536 + t] = h; wsw[98304 + t] = f2bf(f - bf2f(h));
  }
  for (int t = t0; t < 262144; t += stride)
    wsw[131072 + t] = f2bf(Wv[t]);
}

template<bool WS>
__global__ __launch_bounds__(BDIM, 4)   // force VGPR<=128 -> 2 blocks/CU
void axial_attn(const float* __restrict__ x,
                const float* __restrict__ bq, const float* __restrict__ bk,
                const float* __restrict__ bv,
                const float* __restrict__ rel_h, const float* __restrict__ rel_w,
                const float* __restrict__ Wq, const float* __restrict__ Wk,
                const float* __restrict__ Wv,
                const unsigned short* __restrict__ wsw,
                float* __restrict__ out)
{
  extern __shared__ unsigned short S[];

  const int bid = blockIdx.x;
  const int b = bid >> 6, h = bid & 63;
  const int tid = threadIdx.x;
  const int wave = tid >> 6, lane = tid & 63;
  const int lg = lane >> 4, li = lane & 15;
  const int mt = wave >> 1;          // 16-row m-strip (w rows)
  const int nt = wave & 1;           // n-tile half
  const int npair = nt * 2;

  const f32x4 z4 = {0.f, 0.f, 0.f, 0.f};
  f32x4 accQ[2] = {z4, z4}, accK[2] = {z4, z4};
  bf16x8 xa[16];                     // x hi A-frags, full K=512 (64 VGPRs)

  const int xw  = tid & 63;          // staging: lane = w
  const int xc8 = (tid >> 6) << 3;   // 8 consecutive c per thread
  const int wo  = tid >> 3;          // weight staging: o row
  const int wj8 = (tid & 7) << 3;    // 8 c per thread

  // ================= Phase 1: Q,K projection, 8 chunks of c=64 =================
  #pragma unroll
  for (int cc = 0; cc < 8; ++cc){
    const int c0 = cc << 6;
    { // x stage: coalesced scalar loads (wave = 256B row), 8B conflict-free LDS writes
      const float* xp = x + (size_t)(b * 512 + c0 + xc8) * 4096 + h * 64 + xw;
      float f[8];
      #pragma unroll
      for (int i = 0; i < 8; ++i) f[i] = xp[(size_t)i * 4096];
      #pragma unroll
      for (int half = 0; half < 2; ++half){
        union { unsigned short s[4]; uint2 v; } ph, pl;
        #pragma unroll
        for (int j = 0; j < 4; ++j){
          const float ff = f[half * 4 + j];
          ph.s[j] = f2bf(ff);
          pl.s[j] = f2bf(ff - bf2f(ph.s[j]));
        }
        *(uint2*)(S + XH + xw * 72 + xc8 + half * 4) = ph.v;
        *(uint2*)(S + XL + xw * 72 + xc8 + half * 4) = pl.v;
      }
    }
    if (WS){ // pre-converted weights: 1 int4 per buffer per thread
      *(int4*)(S + WQH + wo * 72 + wj8) = *(const int4*)(wsw +     0 + wo * 512 + c0 + wj8);
      *(int4*)(S + WQL + wo * 72 + wj8) = *(const int4*)(wsw + 32768 + wo * 512 + c0 + wj8);
      *(int4*)(S + WKH + wo * 72 + wj8) = *(const int4*)(wsw + 65536 + wo * 512 + c0 + wj8);
      *(int4*)(S + WKL + wo * 72 + wj8) = *(const int4*)(wsw + 98304 + wo * 512 + c0 + wj8);
    } else {
      #pragma unroll
      for (int mi = 0; mi < 2; ++mi){
        const float* src = (mi ? Wk : Wq) + wo * 512 + c0 + wj8;
        const float4 f0 = *(const float4*)src, f1 = *(const float4*)(src + 4);
        const float ff[8] = {f0.x,f0.y,f0.z,f0.w,f1.x,f1.y,f1.z,f1.w};
        union { unsigned short s[8]; int4 v; } ph, pl;
        #pragma unroll
        for (int j = 0; j < 8; ++j){
          ph.s[j] = f2bf(ff[j]);
          pl.s[j] = f2bf(ff[j] - bf2f(ph.s[j]));
        }
        *(int4*)(S + (mi ? WKH : WQH) + wo * 72 + wj8) = ph.v;
        *(int4*)(S + (mi ? WKL : WQL) + wo * 72 + wj8) = pl.v;
      }
    }
    __syncthreads();
    const int arow = (mt * 16 + li) * 72;
    #pragma unroll
    for (int ks = 0; ks < 2; ++ks){
      const int ko = ks * 32 + lg * 8;
      const bf16x8 ah = *(const bf16x8*)(S + XH + arow + ko);
      const bf16x8 al = *(const bf16x8*)(S + XL + arow + ko);
      xa[cc * 2 + ks] = ah;          // keep hi frag for V-proj
      #pragma unroll
      for (int nj = 0; nj < 2; ++nj){
        const int brow = ((npair + nj) * 16 + li) * 72 + ko;
        const bf16x8 bhq = *(const bf16x8*)(S + WQH + brow);
        const bf16x8 blq = *(const bf16x8*)(S + WQL + brow);
        const bf16x8 bhk = *(const bf16x8*)(S + WKH + brow);
        const bf16x8 blk = *(const bf16x8*)(S + WKL + brow);
        accQ[nj] = MFMA16(ah, bhq, accQ[nj]);
        accQ[nj] = MFMA16(ah, blq, accQ[nj]);
        accQ[nj] = MFMA16(al, bhq, accQ[nj]);
        accK[nj] = MFMA16(ah, bhk, accK[nj]);
        accK[nj] = MFMA16(ah, blk, accK[nj]);
        accK[nj] = MFMA16(al, bhk, accK[nj]);
      }
    }
    __syncthreads();
  }

  // ============ Phase 1b: biases + write Q,K hi/lo [row][o] ============
  #pragma unroll
  for (int nj = 0; nj < 2; ++nj){
    const int o = (npair + nj) * 16 + li;
    const float qb = bq[o] + rel_h[o * 512 + h];
    const float bko = bk[o];
    #pragma unroll
    for (int r = 0; r < 4; ++r){
      const int row = mt * 16 + lg * 4 + r;     // w for Q, v for K
      const float qv = accQ[nj][r] + qb;
      const unsigned short qhi = f2bf(qv);
      S[QH + row * 72 + o] = qhi;
      S[QL + row * 72 + o] = f2bf(qv - bf2f(qhi));
      const float kv = accK[nj][r] + bko + rel_w[o * 512 + row];
      const unsigned short khi = f2bf(kv);
      S[KH + row * 72 + o] = khi;
      S[KL + row * 72 + o] = f2bf(kv - bf2f(khi));
    }
  }
  __syncthreads();

  // ============ Phase 2: S = Q K^T (split), softmax -> att (waves 0..3) ============
  if (wave < 4){
    f32x4 s[4] = {z4, z4, z4, z4};
    #pragma unroll
    for (int ks = 0; ks < 2; ++ks){
      const int ko = ks * 32 + lg * 8;
      const bf16x8 aqh = *(const bf16x8*)(S + QH + (wave * 16 + li) * 72 + ko);
      const bf16x8 aql = *(const bf16x8*)(S + QL + (wave * 16 + li) * 72 + ko);
      #pragma unroll
      for (int ntt = 0; ntt < 4; ++ntt){
        const bf16x8 bh = *(const bf16x8*)(S + KH + (ntt * 16 + li) * 72 + ko);
        const bf16x8 bl = *(const bf16x8*)(S + KL + (ntt * 16 + li) * 72 + ko);
        s[ntt] = MFMA16(aqh, bh, s[ntt]);
        s[ntt] = MFMA16(aqh, bl, s[ntt]);
        s[ntt] = MFMA16(aql, bh, s[ntt]);
      }
    }
    #pragma unroll
    for (int r = 0; r < 4; ++r){
      float mx = fmaxf(fmaxf(s[0][r], s[1][r]), fmaxf(s[2][r], s[3][r]));
      mx = fmaxf(mx, __shfl_xor(mx, 1));
      mx = fmaxf(mx, __shfl_xor(mx, 2));
      mx = fmaxf(mx, __shfl_xor(mx, 4));
      mx = fmaxf(mx, __shfl_xor(mx, 8));
      const float e0 = __expf(s[0][r] - mx), e1 = __expf(s[1][r] - mx);
      const float e2 = __expf(s[2][r] - mx), e3 = __expf(s[3][r] - mx);
      float sum = e0 + e1 + e2 + e3;
      sum += __shfl_xor(sum, 1); sum += __shfl_xor(sum, 2);
      sum += __shfl_xor(sum, 4); sum += __shfl_xor(sum, 8);
      const float inv = 1.f / sum;
      const int row = wave * 16 + lg * 4 + r;
      S[ATT + row * 72 +  0 + li] = f2bf(e0 * inv);
      S[ATT + row * 72 + 16 + li] = f2bf(e1 * inv);
      S[ATT + row * 72 + 32 + li] = f2bf(e2 * inv);
      S[ATT + row * 72 + 48 + li] = f2bf(e3 * inv);
    }
  }
  __syncthreads();

  // ============ Phase 3: 16 d-chunks of 32, double-buffered Wv ============
  auto loadWv = [&](int d0, int4* r){
    #pragma unroll
    for (int it = 0; it < 4; ++it){
      const int idx = tid + it * BDIM;
      const int d = idx >> 6, j8 = (idx & 63) << 3;
      if (WS){
        r[it] = *(const int4*)(wsw + 131072 + (d0 + d) * 512 + j8);
      } else {
        const float* src = Wv + (d0 + d) * 512 + j8;
        const float4 f0 = *(const float4*)src, f1 = *(const float4*)(src + 4);
        const float ff[8] = {f0.x,f0.y,f0.z,f0.w,f1.x,f1.y,f1.z,f1.w};
        union { unsigned short s[8]; int4 v; } p;
        #pragma unroll
        for (int j = 0; j < 8; ++j) p.s[j] = f2bf(ff[j]);
        r[it] = p.v;
      }
    }
  };
  auto writeWv = [&](int base, const int4* r){
    #pragma unroll
    for (int it = 0; it < 4; ++it){
      const int idx = tid + it * BDIM;
      const int d = idx >> 6, j8 = (idx & 63) << 3;
      *(int4*)(S + base + d * 520 + j8) = r[it];
    }
  };

  { // prologue: stage d-chunk 0 into WVB0
    int4 r[4];
    loadWv(0, r);
    writeWv(WVB0, r);
  }
  __syncthreads();

  for (int dc = 0; dc < 16; ++dc){
    const int cur = dc & 1;
    const int WB  = cur ? WVB1 : WVB0;
    const int WBn = cur ? WVB0 : WVB1;
    const bool pf = (dc < 15);
    int4 r[4];
    if (pf) loadWv((dc + 1) * 32, r);     // issue loads early: latency under MFMAs

    // V-proj: V[v, d] for this wave's (mt v-strip, nt d-tile); A from registers
    f32x4 accV = z4;
    const int bbase = (nt * 16 + li) * 520 + lg * 8;
    #pragma unroll
    for (int ks = 0; ks < 16; ++ks){
      const bf16x8 bb = *(const bf16x8*)(S + WB + bbase + ks * 32);
      accV = MFMA16(xa[ks], bb, accV);
    }
    if (pf) writeWv(WBn, r);              // write next buffer (other region)

    { // Vt[d][v] write, 8B per lane
      const int d = nt * 16 + li;
      const float bvd = bv[dc * 32 + d];
      union { unsigned short s[4]; uint2 v; } p;
      #pragma unroll
      for (int rr = 0; rr < 4; ++rr) p.s[rr] = f2bf(accV[rr] + bvd);
      *(uint2*)(S + VT + d * 72 + mt * 16 + lg * 4) = p.v;
    }
    __syncthreads();

    // AV: D[w, d] = att[w,:] . V[:,d]  (A=att, B=Vt) -> float4 stores along w
    f32x4 accO = z4;
    #pragma unroll
    for (int ks = 0; ks < 2; ++ks){
      const int ko = ks * 32 + lg * 8;
      const bf16x8 a  = *(const bf16x8*)(S + ATT + (mt * 16 + li) * 72 + ko);
      const bf16x8 bb = *(const bf16x8*)(S + VT  + (nt * 16 + li) * 72 + ko);
      accO = MFMA16(a, bb, accO);
    }
    {
      const int d  = dc * 32 + nt * 16 + li;
      const int w0 = mt * 16 + lg * 4;
      float4 o4 = {accO[0], accO[1], accO[2], accO[3]};
      *(float4*)(out + (size_t)(b * 512 + d) * 4096 + h * 64 + w0) = o4;
    }
    __syncthreads();
  }
}

extern "C" void kernel_launch(void* const* d_in, const int* in_sizes, int n_in,
                              void* d_out, int out_size, void* d_ws, size_t ws_size,
                              hipStream_t stream){
  const float* x     = (const float*)d_in[0];
  const float* Wq    = (const float*)d_in[1];
  const float* bq    = (const float*)d_in[2];
  const float* Wk    = (const float*)d_in[3];
  const float* bk    = (const float*)d_in[4];
  const float* Wv    = (const float*)d_in[5];
  const float* bv    = (const float*)d_in[6];
  const float* rel_h = (const float*)d_in[7];
  const float* rel_w = (const float*)d_in[8];
  float* out = (float*)d_out;

  const dim3 grid(1024), blk(BDIM);

  if (ws_size >= 786432){
    convert_w<<<1024, 256, 0, stream>>>(Wq, Wk, Wv, (unsigned short*)d_ws);
    axial_attn<true><<<grid, blk, SMEM_BYTES, stream>>>(x, bq, bk, bv, rel_h, rel_w,
                                                        Wq, Wk, Wv,
                                                        (const unsigned short*)d_ws, out);
  } else {
    axial_attn<false><<<grid, blk, SMEM_BYTES, stream>>>(x, bq, bk, bv, rel_h, rel_w,
                                                         Wq, Wk, Wv, nullptr, out);
  }
}